// Round 7
// baseline (265.934 us; speedup 1.0000x reference)
//
#include <hip/hip_runtime.h>

using bf16x8 = __attribute__((ext_vector_type(8))) short;
using f32x4  = __attribute__((ext_vector_type(4))) float;

static constexpr int NB = 8;
static constexpr int NS = 4096;
static constexpr int NH = 16;
static constexpr int ND = 128;
static constexpr int BH = NB * NH;   // 128
static constexpr int HD = NH * ND;   // 2048

// round-to-nearest-even pack of two fp32 -> bf16x2 in a uint32
__device__ inline unsigned pack2(float a, float b) {
    unsigned ua = __float_as_uint(a), ub = __float_as_uint(b);
    ua += 0x7fffu + ((ua >> 16) & 1u);
    ub += 0x7fffu + ((ub >> 16) & 1u);
    return (ua >> 16) | (ub & 0xffff0000u);
}

__device__ inline int swz2(int row) { return (row ^ (row >> 2)) & 3; }

// ---------------------------------------------------------------------------
// Kernel 1: per (b,h,S-chunk): pctx_t[e][d] = sum_s exp(k[s,d]) * v[s,e]
// (TRANSPOSED, fp32) + pden[d] = sum_s exp(k[s,d]).
// R7: 32-s tiles (light critical path), NC=8 (1024 blocks), 32KB LDS,
// launch_bounds(256,3) for ~12 waves/CU. LDS rows [128][32] bf16; 8B chunks
// with slot = sg ^ (swz2(row)<<1) (bit0 preserved -> 16B fragment reads OK).
// ---------------------------------------------------------------------------
template <int NC>
__global__ __launch_bounds__(256, 3)
void ctx_mfma(const float* __restrict__ kk, const float* __restrict__ vv,
              float* __restrict__ pctx_t, float* __restrict__ pden) {
    constexpr int SC = NS / NC;
    constexpr int T  = SC / 32;
    __shared__ __align__(16) unsigned short aL[2][128][32];  // exp(k)^T tiles
    __shared__ __align__(16) unsigned short bL[2][128][32];  // v^T tiles

    const int blk = blockIdx.x, bh = blk / NC, c = blk % NC;
    const int b = bh >> 4, h = bh & 15;
    const int tid = threadIdx.x, lane = tid & 63, wv = tid >> 6;
    const int r15 = lane & 15, hi = lane >> 4;
    const size_t base = (size_t)b * NS * HD + (size_t)h * ND;

    const int d0 = (tid & 31) * 4;   // 4 consecutive d per thread
    const int sg = tid >> 5;         // s-chunk 0..7 (4 s each)

    float dsum[4] = {0.f, 0.f, 0.f, 0.f};

    auto issue = [&](int t, float4* kq, float4* vq) {
        const size_t s0 = (size_t)(c * SC + t * 32 + 4 * sg);
        const float* kp = kk + base + s0 * HD + d0;
        const float* vp = vv + base + s0 * HD + d0;
#pragma unroll
        for (int j = 0; j < 4; ++j) kq[j] = *(const float4*)(kp + (size_t)j * HD);
#pragma unroll
        for (int j = 0; j < 4; ++j) vq[j] = *(const float4*)(vp + (size_t)j * HD);
    };

    f32x4 acc[4][4];
#pragma unroll
    for (int m = 0; m < 4; ++m)
#pragma unroll
        for (int n = 0; n < 4; ++n) acc[m][n] = (f32x4){0.f, 0.f, 0.f, 0.f};

    const int wd = wv >> 1, we = wv & 1;        // wave's 64x64 quadrant

    auto mma = [&](int buf) {
        bf16x8 af[4], bfv[4];
#pragma unroll
        for (int m = 0; m < 4; ++m) {
            const int row = 64 * wd + 16 * m + r15;
            const int pc0 = (2 * hi) ^ (swz2(row) << 1);
            af[m] = *(const bf16x8*)&aL[buf][row][pc0 * 4];
        }
#pragma unroll
        for (int n = 0; n < 4; ++n) {
            const int row = 64 * we + 16 * n + r15;
            const int pc0 = (2 * hi) ^ (swz2(row) << 1);
            bfv[n] = *(const bf16x8*)&bL[buf][row][pc0 * 4];
        }
#pragma unroll
        for (int m = 0; m < 4; ++m)
#pragma unroll
            for (int n = 0; n < 4; ++n)
                acc[m][n] = __builtin_amdgcn_mfma_f32_16x16x32_bf16(
                    af[m], bfv[n], acc[m][n], 0, 0, 0);
    };

    float4 kq[4], vq[4];
    issue(0, kq, vq);

    for (int t = 0; t < T; ++t) {
        // pack tile t from registers (vmcnt wait lands here)
        const float* kf = (const float*)kq;
        const float* vf = (const float*)vq;
        uint2 pa[4], pb[4];
#pragma unroll
        for (int i = 0; i < 4; ++i) {
            float e0 = __expf(kf[0 + i]), e1 = __expf(kf[4 + i]);
            float e2 = __expf(kf[8 + i]), e3 = __expf(kf[12 + i]);
            dsum[i] += (e0 + e1) + (e2 + e3);
            pa[i] = make_uint2(pack2(e0, e1), pack2(e2, e3));
            pb[i] = make_uint2(pack2(vf[0 + i], vf[4 + i]),
                               pack2(vf[8 + i], vf[12 + i]));
        }
        if (t + 1 < T) issue(t + 1, kq, vq);   // next loads fly over store+sync+mma
        const int buf = t & 1;
#pragma unroll
        for (int i = 0; i < 4; ++i) {
            const int row = d0 + i;
            const int slot = sg ^ (swz2(row) << 1);
            *(uint2*)&aL[buf][row][slot * 4] = pa[i];
            *(uint2*)&bL[buf][row][slot * 4] = pb[i];
        }
        __syncthreads();                        // tile t staged; buf free (sync t-1)
        mma(buf);
    }

    // denominator: per-d partials over this thread's 4 s columns x T tiles
    __syncthreads();
    float* dr = (float*)&aL[0][0][0];           // 8 x 128 floats = 4 KB
    *(float4*)&dr[sg * 128 + d0] = make_float4(dsum[0], dsum[1], dsum[2], dsum[3]);
    __syncthreads();
    if (tid < 128) {
        float s = 0.f;
#pragma unroll
        for (int r = 0; r < 8; ++r) s += dr[r * 128 + tid];
        pden[(size_t)blk * 128 + tid] = s;
    }

    // write transposed partial context: pctx_t[e][d], float4 along d
    float* po = pctx_t + (size_t)blk * (ND * ND);
#pragma unroll
    for (int m = 0; m < 4; ++m)
#pragma unroll
        for (int n = 0; n < 4; ++n) {
            const int e  = 64 * we + 16 * n + r15;
            const int dd = 64 * wd + 16 * m + 4 * hi;
            *(f32x4*)&po[e * ND + dd] = acc[m][n];
        }
}

// ---------------------------------------------------------------------------
// Kernel 2: sum chunk partials, normalize, emit bf16 ctx_t[e][d]
// ---------------------------------------------------------------------------
__global__ void ctx_combine(const float* __restrict__ pctx_t,
                            const float* __restrict__ pden,
                            unsigned short* __restrict__ ctx_t, int nc) {
    const int gid = blockIdx.x * 256 + threadIdx.x;      // over BH*16384/2
    const size_t w = (size_t)gid * 2;
    const int bh = (int)(w >> 14);
    const int wi = (int)(w & 16383);
    const int dd = wi & 127;
    float s0 = 0.f, s1 = 0.f, dn0 = 0.f, dn1 = 0.f;
    for (int c2 = 0; c2 < nc; ++c2) {
        const float* p  = pctx_t + (((size_t)(bh * nc + c2)) << 14) + wi;
        const float* pd = pden + (size_t)(bh * nc + c2) * ND + dd;
        s0 += p[0]; s1 += p[1];
        dn0 += pd[0]; dn1 += pd[1];
    }
    *(unsigned*)&ctx_t[w] = pack2(s0 / dn0, s1 / dn1);
}

// ---------------------------------------------------------------------------
// Kernel 3: out[s][e] = (1/sum_d exp(q[s,d])) * sum_d exp(q[s,d]) * ctx[d][e]
// ---------------------------------------------------------------------------
__global__ __launch_bounds__(256, 2)
void out_mfma(const float* __restrict__ qq,
              const unsigned short* __restrict__ ctx_t,
              float* __restrict__ out) {
    __shared__ __align__(16) unsigned short cL[128][128];    // 32KB ctx_t
    __shared__ __align__(16) unsigned short qL[2][32][128];  // 16KB q tiles
    __shared__ float qd[2][32];

    const int blk = blockIdx.x, bh = blk >> 3, c = blk & 7;
    const int b = bh >> 4, h = bh & 15;
    const int tid = threadIdx.x, lane = tid & 63, wv = tid >> 6;
    const int r15 = lane & 15, hi = lane >> 4;

    // stage ctx_t -> LDS (swizzled: chunk ^ (row&15)); 2048 uint4 total
    {
        const unsigned short* src = ctx_t + ((size_t)bh << 14);
#pragma unroll
        for (int j = 0; j < 8; ++j) {
            const int g = tid + 256 * j;
            const int e = g >> 4, cs = g & 15;
            uint4 t4 = *(const uint4*)&src[e * 128 + cs * 8];
            *(uint4*)&cL[e][(cs ^ (e & 15)) * 8] = t4;
        }
    }

    const size_t qbase = (size_t)b * NS * HD + (size_t)h * ND;
    const int s_blk = c * 512;

    auto stageq = [&](int t, int buf) {
#pragma unroll
        for (int jj = 0; jj < 2; ++jj) {
            const int g = tid + 256 * jj;
            const int s = g >> 4, cs = g & 15;
            const float* qp = qq + qbase + (size_t)(s_blk + t * 32 + s) * HD + cs * 8;
            float x[8];
            *(float4*)&x[0] = *(const float4*)qp;
            *(float4*)&x[4] = *(const float4*)(qp + 4);
            float ps = 0.f;
            unsigned pw[4];
#pragma unroll
            for (int j2 = 0; j2 < 4; ++j2) {
                float e0 = __expf(x[2 * j2]), e1 = __expf(x[2 * j2 + 1]);
                ps += e0 + e1;
                pw[j2] = pack2(e0, e1);
            }
            ps += __shfl_xor(ps, 1);
            ps += __shfl_xor(ps, 2);
            ps += __shfl_xor(ps, 4);
            ps += __shfl_xor(ps, 8);            // row-sum across the 16 d-chunks
            *(uint4*)&qL[buf][s][(cs ^ (s & 15)) * 8] =
                make_uint4(pw[0], pw[1], pw[2], pw[3]);
            if ((lane & 15) == 0) qd[buf][s] = ps;
        }
    };

    __syncthreads();                             // ctx staged

    // hoist B fragments: wave w covers e in [32w, 32w+32)
    bf16x8 bfr[2][4];
#pragma unroll
    for (int n = 0; n < 2; ++n) {
        const int e = 32 * wv + 16 * n + r15;
#pragma unroll
        for (int ks = 0; ks < 4; ++ks) {
            const int cw = (4 * ks + hi) ^ (e & 15);
            bfr[n][ks] = *(const bf16x8*)&cL[e][cw * 8];
        }
    }

    stageq(0, 0);
    for (int t = 0; t < 16; ++t) {
        __syncthreads();
        if (t + 1 < 16) stageq(t + 1, (t + 1) & 1);
        const int buf = t & 1;

        f32x4 acc[2][2];
#pragma unroll
        for (int m = 0; m < 2; ++m)
#pragma unroll
            for (int n = 0; n < 2; ++n) acc[m][n] = (f32x4){0.f, 0.f, 0.f, 0.f};

#pragma unroll
        for (int ks = 0; ks < 4; ++ks) {
            bf16x8 af[2];
#pragma unroll
            for (int m = 0; m < 2; ++m) {
                const int s = 16 * m + r15;
                const int cw = (4 * ks + hi) ^ (s & 15);
                af[m] = *(const bf16x8*)&qL[buf][s][cw * 8];
            }
#pragma unroll
            for (int m = 0; m < 2; ++m)
#pragma unroll
                for (int n = 0; n < 2; ++n)
                    acc[m][n] = __builtin_amdgcn_mfma_f32_16x16x32_bf16(
                        af[m], bfr[n][ks], acc[m][n], 0, 0, 0);
        }

        // normalize + write
#pragma unroll
        for (int m = 0; m < 2; ++m) {
            const int sl0 = 16 * m + 4 * hi;
            const float i0 = 1.f / qd[buf][sl0];
            const float i1 = 1.f / qd[buf][sl0 + 1];
            const float i2 = 1.f / qd[buf][sl0 + 2];
            const float i3 = 1.f / qd[buf][sl0 + 3];
            const int srow = s_blk + t * 32 + sl0;
            float* ob = out + ((size_t)b * NS + srow) * HD + (size_t)h * ND;
#pragma unroll
            for (int n = 0; n < 2; ++n) {
                const int e = 32 * wv + 16 * n + r15;
                ob[0 * HD + e] = acc[m][n][0] * i0;
                ob[1 * HD + e] = acc[m][n][1] * i1;
                ob[2 * HD + e] = acc[m][n][2] * i2;
                ob[3 * HD + e] = acc[m][n][3] * i3;
            }
        }
    }
}

// ---------------------------------------------------------------------------
extern "C" void kernel_launch(void* const* d_in, const int* in_sizes, int n_in,
                              void* d_out, int out_size, void* d_ws, size_t ws_size,
                              hipStream_t stream) {
    (void)in_sizes; (void)n_in; (void)out_size;
    const float* q = (const float*)d_in[0];
    const float* k = (const float*)d_in[1];
    const float* v = (const float*)d_in[2];
    float* out = (float*)d_out;

    auto need = [](size_t nc) -> size_t {
        return 4ull * ((size_t)BH * nc * ND * ND + (size_t)BH * nc * ND) +
               2ull * (size_t)BH * ND * ND;
    };
    const int nc = (ws_size >= need(8)) ? 8
                 : (ws_size >= need(4)) ? 4
                 : (ws_size >= need(2)) ? 2 : 1;

    float* pctx_t = (float*)d_ws;
    float* pden   = pctx_t + (size_t)BH * nc * ND * ND;
    unsigned short* ctx_t = (unsigned short*)(pden + (size_t)BH * nc * ND);

    if (nc == 8)
        ctx_mfma<8><<<BH * 8, 256, 0, stream>>>(k, v, pctx_t, pden);
    else if (nc == 4)
        ctx_mfma<4><<<BH * 4, 256, 0, stream>>>(k, v, pctx_t, pden);
    else if (nc == 2)
        ctx_mfma<2><<<BH * 2, 256, 0, stream>>>(k, v, pctx_t, pden);
    else
        ctx_mfma<1><<<BH * 1, 256, 0, stream>>>(k, v, pctx_t, pden);

    ctx_combine<<<(BH * ND * ND / 2) / 256, 256, 0, stream>>>(pctx_t, pden, ctx_t, nc);

    out_mfma<<<BH * 8, 256, 0, stream>>>(q, ctx_t, out);
}

// Round 8
// 248.120 us; speedup vs baseline: 1.0718x; 1.0718x over previous
//
#include <hip/hip_runtime.h>

using bf16x8 = __attribute__((ext_vector_type(8))) short;
using f32x4  = __attribute__((ext_vector_type(4))) float;

static constexpr int NB = 8;
static constexpr int NS = 4096;
static constexpr int NH = 16;
static constexpr int ND = 128;
static constexpr int BH = NB * NH;   // 128
static constexpr int HD = NH * ND;   // 2048

// round-to-nearest-even pack of two fp32 -> bf16x2 in a uint32
__device__ inline unsigned pack2(float a, float b) {
    unsigned ua = __float_as_uint(a), ub = __float_as_uint(b);
    ua += 0x7fffu + ((ua >> 16) & 1u);
    ub += 0x7fffu + ((ub >> 16) & 1u);
    return (ua >> 16) | (ub & 0xffff0000u);
}

__device__ inline int swz3(int row) { return (row ^ (row >> 2)) & 7; }

// ---------------------------------------------------------------------------
// Kernel 1 (R8): head-PAIR blocks for contiguous 1KB loads.
// Block = 1024 thr (16 waves) on (b, head-pair hp, s-chunk c).
// One wave-load = 64 lanes x float4 = 1KB contiguous (2 heads x 128 d fp32).
// Waves 0-7 stage K (rows 4w..4w+4 of the 32-s tile), waves 8-15 stage V.
// LDS [buf][head][128 rows][32 s] bf16 (64KB), 8B chunks, slot = cs ^ swz3(row).
// MFMA: per head 8 waves, each 32d x 64e (acc[2][4]); K-dim 32 = 1 mfma step.
// ---------------------------------------------------------------------------
template <int NC>
__global__ __launch_bounds__(1024, 4)
void ctx_mfma(const float* __restrict__ kk, const float* __restrict__ vv,
              float* __restrict__ pctx_t, float* __restrict__ pden) {
    constexpr int SC = NS / NC;
    constexpr int T  = SC / 32;       // tiles per block (even)
    __shared__ __align__(16) unsigned short aL[2][2][128][32]; // [buf][head] exp(k)^T
    __shared__ __align__(16) unsigned short bL[2][2][128][32]; // [buf][head] v^T

    const int blk = blockIdx.x, bhp = blk / NC, c = blk % NC;
    const int b = bhp >> 3, hp = bhp & 7;
    const int tid = threadIdx.x, l = tid & 63, wv = tid >> 6;  // wv 0..15
    const int r15 = l & 15, hi = l >> 4;

    const size_t base = (size_t)b * NS * HD + (size_t)hp * 256; // 2-head slice

    // ---- staging role ----
    const bool isK = (wv < 8);
    const int  wk  = isK ? wv : (wv - 8);   // 0..7 -> rows 4wk..4wk+4
    const float* src = isK ? kk : vv;
    const int hl = l >> 5;                  // head this lane loads
    const int d0 = (l & 31) << 2;           // 4 d per lane

    float dsum[4] = {0.f, 0.f, 0.f, 0.f};

    auto issue = [&](int t, float4* q) {
        const size_t s0 = (size_t)(c * SC + t * 32 + 4 * wk);
        const float* p = src + base + s0 * HD + (size_t)l * 4;
#pragma unroll
        for (int j = 0; j < 4; ++j) q[j] = *(const float4*)(p + (size_t)j * HD);
    };

    auto pack_store = [&](int buf, const float4* q) {
        const float* f = (const float*)q;   // f[4j+i] = (s=4wk+j, d=d0+i)
        if (isK) {
#pragma unroll
            for (int i = 0; i < 4; ++i) {
                float e0 = __expf(f[0 + i]), e1 = __expf(f[4 + i]);
                float e2 = __expf(f[8 + i]), e3 = __expf(f[12 + i]);
                dsum[i] += (e0 + e1) + (e2 + e3);
                const int row = d0 + i;
                const int slot = wk ^ swz3(row);
                *(uint2*)&aL[buf][hl][row][slot * 4] =
                    make_uint2(pack2(e0, e1), pack2(e2, e3));
            }
        } else {
#pragma unroll
            for (int i = 0; i < 4; ++i) {
                const int row = d0 + i;
                const int slot = wk ^ swz3(row);
                *(uint2*)&bL[buf][hl][row][slot * 4] =
                    make_uint2(pack2(f[0 + i], f[4 + i]),
                               pack2(f[8 + i], f[12 + i]));
            }
        }
    };

    // ---- mma role: head hm, sub-tile (wd: 32-d strip, we: 64-e half) ----
    const int hm = wv >> 3, sub = wv & 7, wd = sub >> 1, we = sub & 1;

    f32x4 acc[2][4];
#pragma unroll
    for (int m = 0; m < 2; ++m)
#pragma unroll
        for (int n = 0; n < 4; ++n) acc[m][n] = (f32x4){0.f, 0.f, 0.f, 0.f};

    auto mma = [&](int buf) {
        bf16x8 af[2], bf[4];
#pragma unroll
        for (int m = 0; m < 2; ++m) {
            const int row = 32 * wd + 16 * m + r15;
            const int v = swz3(row);
            uint2 r0 = *(const uint2*)&aL[buf][hm][row][((2 * hi) ^ v) * 4];
            uint2 r1 = *(const uint2*)&aL[buf][hm][row][((2 * hi + 1) ^ v) * 4];
            uint4 u = make_uint4(r0.x, r0.y, r1.x, r1.y);
            af[m] = __builtin_bit_cast(bf16x8, u);
        }
#pragma unroll
        for (int n = 0; n < 4; ++n) {
            const int row = 64 * we + 16 * n + r15;
            const int v = swz3(row);
            uint2 r0 = *(const uint2*)&bL[buf][hm][row][((2 * hi) ^ v) * 4];
            uint2 r1 = *(const uint2*)&bL[buf][hm][row][((2 * hi + 1) ^ v) * 4];
            uint4 u = make_uint4(r0.x, r0.y, r1.x, r1.y);
            bf[n] = __builtin_bit_cast(bf16x8, u);
        }
#pragma unroll
        for (int m = 0; m < 2; ++m)
#pragma unroll
            for (int n = 0; n < 4; ++n)
                acc[m][n] = __builtin_amdgcn_mfma_f32_16x16x32_bf16(
                    af[m], bf[n], acc[m][n], 0, 0, 0);
    };

    // ---- main loop: dual staging reg sets, 1 barrier per tile ----
    float4 qa[4], qb[4];
    issue(0, qa);
    for (int t = 0; t < T; t += 2) {
        if (t + 1 < T) issue(t + 1, qb);   // in flight over pack(qa)+sync+mma
        pack_store(t & 1, qa);             // vmcnt waits only on qa's loads
        __syncthreads();                   // tile staged; buf safe (sync t-1)
        mma(t & 1);
        if (t + 2 < T) issue(t + 2, qa);
        pack_store((t + 1) & 1, qb);
        __syncthreads();
        mma((t + 1) & 1);
    }

    // ---- denominator reduction: dr[head][8 kwaves][128 d] in aL scratch ----
    __syncthreads();
    float* dr = (float*)&aL[0][0][0][0];   // 8 KB
    if (isK)
        *(float4*)&dr[(hl * 8 + wk) * 128 + d0] =
            make_float4(dsum[0], dsum[1], dsum[2], dsum[3]);
    __syncthreads();
    if (tid < 256) {
        const int head = tid >> 7, d = tid & 127;
        float s = 0.f;
#pragma unroll
        for (int w = 0; w < 8; ++w) s += dr[(head * 8 + w) * 128 + d];
        const int bh_g = b * 16 + hp * 2 + head;
        pden[((size_t)bh_g * NC + c) * ND + d] = s;
    }

    // ---- write transposed partial context for head hm ----
    float* po = pctx_t + (((size_t)(b * 16 + hp * 2 + hm) * NC + c) << 14);
#pragma unroll
    for (int m = 0; m < 2; ++m)
#pragma unroll
        for (int n = 0; n < 4; ++n) {
            const int e  = 64 * we + 16 * n + r15;
            const int dd = 32 * wd + 16 * m + 4 * hi;
            *(f32x4*)&po[e * ND + dd] = acc[m][n];
        }
}

// ---------------------------------------------------------------------------
// Kernel 2: sum chunk partials, normalize, emit bf16 ctx_t[e][d]
// ---------------------------------------------------------------------------
__global__ void ctx_combine(const float* __restrict__ pctx_t,
                            const float* __restrict__ pden,
                            unsigned short* __restrict__ ctx_t, int nc) {
    const int gid = blockIdx.x * 256 + threadIdx.x;      // over BH*16384/2
    const size_t w = (size_t)gid * 2;
    const int bh = (int)(w >> 14);
    const int wi = (int)(w & 16383);
    const int dd = wi & 127;
    float s0 = 0.f, s1 = 0.f, dn0 = 0.f, dn1 = 0.f;
    for (int c2 = 0; c2 < nc; ++c2) {
        const float* p  = pctx_t + (((size_t)(bh * nc + c2)) << 14) + wi;
        const float* pd = pden + (size_t)(bh * nc + c2) * ND + dd;
        s0 += p[0]; s1 += p[1];
        dn0 += pd[0]; dn1 += pd[1];
    }
    *(unsigned*)&ctx_t[w] = pack2(s0 / dn0, s1 / dn1);
}

// ---------------------------------------------------------------------------
// Kernel 3: out[s][e] = (1/sum_d exp(q[s,d])) * sum_d exp(q[s,d]) * ctx[d][e]
// (unchanged from R7)
// ---------------------------------------------------------------------------
__global__ __launch_bounds__(256, 2)
void out_mfma(const float* __restrict__ qq,
              const unsigned short* __restrict__ ctx_t,
              float* __restrict__ out) {
    __shared__ __align__(16) unsigned short cL[128][128];    // 32KB ctx_t
    __shared__ __align__(16) unsigned short qL[2][32][128];  // 16KB q tiles
    __shared__ float qd[2][32];

    const int blk = blockIdx.x, bh = blk >> 3, c = blk & 7;
    const int b = bh >> 4, h = bh & 15;
    const int tid = threadIdx.x, lane = tid & 63, wv = tid >> 6;
    const int r15 = lane & 15, hi = lane >> 4;

    {
        const unsigned short* src = ctx_t + ((size_t)bh << 14);
#pragma unroll
        for (int j = 0; j < 8; ++j) {
            const int g = tid + 256 * j;
            const int e = g >> 4, cs = g & 15;
            uint4 t4 = *(const uint4*)&src[e * 128 + cs * 8];
            *(uint4*)&cL[e][(cs ^ (e & 15)) * 8] = t4;
        }
    }

    const size_t qbase = (size_t)b * NS * HD + (size_t)h * ND;
    const int s_blk = c * 512;

    auto stageq = [&](int t, int buf) {
#pragma unroll
        for (int jj = 0; jj < 2; ++jj) {
            const int g = tid + 256 * jj;
            const int s = g >> 4, cs = g & 15;
            const float* qp = qq + qbase + (size_t)(s_blk + t * 32 + s) * HD + cs * 8;
            float x[8];
            *(float4*)&x[0] = *(const float4*)qp;
            *(float4*)&x[4] = *(const float4*)(qp + 4);
            float ps = 0.f;
            unsigned pw[4];
#pragma unroll
            for (int j2 = 0; j2 < 4; ++j2) {
                float e0 = __expf(x[2 * j2]), e1 = __expf(x[2 * j2 + 1]);
                ps += e0 + e1;
                pw[j2] = pack2(e0, e1);
            }
            ps += __shfl_xor(ps, 1);
            ps += __shfl_xor(ps, 2);
            ps += __shfl_xor(ps, 4);
            ps += __shfl_xor(ps, 8);
            *(uint4*)&qL[buf][s][(cs ^ (s & 15)) * 8] =
                make_uint4(pw[0], pw[1], pw[2], pw[3]);
            if ((lane & 15) == 0) qd[buf][s] = ps;
        }
    };

    __syncthreads();

    bf16x8 bfr[2][4];
#pragma unroll
    for (int n = 0; n < 2; ++n) {
        const int e = 32 * wv + 16 * n + r15;
#pragma unroll
        for (int ks = 0; ks < 4; ++ks) {
            const int cw = (4 * ks + hi) ^ (e & 15);
            bfr[n][ks] = *(const bf16x8*)&cL[e][cw * 8];
        }
    }

    stageq(0, 0);
    for (int t = 0; t < 16; ++t) {
        __syncthreads();
        if (t + 1 < 16) stageq(t + 1, (t + 1) & 1);
        const int buf = t & 1;

        f32x4 acc[2][2];
#pragma unroll
        for (int m = 0; m < 2; ++m)
#pragma unroll
            for (int n = 0; n < 2; ++n) acc[m][n] = (f32x4){0.f, 0.f, 0.f, 0.f};

#pragma unroll
        for (int ks = 0; ks < 4; ++ks) {
            bf16x8 af[2];
#pragma unroll
            for (int m = 0; m < 2; ++m) {
                const int s = 16 * m + r15;
                const int cw = (4 * ks + hi) ^ (s & 15);
                af[m] = *(const bf16x8*)&qL[buf][s][cw * 8];
            }
#pragma unroll
            for (int m = 0; m < 2; ++m)
#pragma unroll
                for (int n = 0; n < 2; ++n)
                    acc[m][n] = __builtin_amdgcn_mfma_f32_16x16x32_bf16(
                        af[m], bfr[n][ks], acc[m][n], 0, 0, 0);
        }

#pragma unroll
        for (int m = 0; m < 2; ++m) {
            const int sl0 = 16 * m + 4 * hi;
            const float i0 = 1.f / qd[buf][sl0];
            const float i1 = 1.f / qd[buf][sl0 + 1];
            const float i2 = 1.f / qd[buf][sl0 + 2];
            const float i3 = 1.f / qd[buf][sl0 + 3];
            const int srow = s_blk + t * 32 + sl0;
            float* ob = out + ((size_t)b * NS + srow) * HD + (size_t)h * ND;
#pragma unroll
            for (int n = 0; n < 2; ++n) {
                const int e = 32 * wv + 16 * n + r15;
                ob[0 * HD + e] = acc[m][n][0] * i0;
                ob[1 * HD + e] = acc[m][n][1] * i1;
                ob[2 * HD + e] = acc[m][n][2] * i2;
                ob[3 * HD + e] = acc[m][n][3] * i3;
            }
        }
    }
}

// ---------------------------------------------------------------------------
extern "C" void kernel_launch(void* const* d_in, const int* in_sizes, int n_in,
                              void* d_out, int out_size, void* d_ws, size_t ws_size,
                              hipStream_t stream) {
    (void)in_sizes; (void)n_in; (void)out_size;
    const float* q = (const float*)d_in[0];
    const float* k = (const float*)d_in[1];
    const float* v = (const float*)d_in[2];
    float* out = (float*)d_out;

    auto need = [](size_t nc) -> size_t {
        return 4ull * ((size_t)BH * nc * ND * ND + (size_t)BH * nc * ND) +
               2ull * (size_t)BH * ND * ND;
    };
    const int nc = (ws_size >= need(4)) ? 4 : (ws_size >= need(2)) ? 2 : 1;

    float* pctx_t = (float*)d_ws;
    float* pden   = pctx_t + (size_t)BH * nc * ND * ND;
    unsigned short* ctx_t = (unsigned short*)(pden + (size_t)BH * nc * ND);

    if (nc == 4)
        ctx_mfma<4><<<64 * 4, 1024, 0, stream>>>(k, v, pctx_t, pden);
    else if (nc == 2)
        ctx_mfma<2><<<64 * 2, 1024, 0, stream>>>(k, v, pctx_t, pden);
    else
        ctx_mfma<1><<<64 * 1, 1024, 0, stream>>>(k, v, pctx_t, pden);

    ctx_combine<<<(BH * ND * ND / 2) / 256, 256, 0, stream>>>(pctx_t, pden, ctx_t, nc);

    out_mfma<<<BH * 8, 256, 0, stream>>>(q, ctx_t, out);
}